// Round 3
// baseline (181.019 us; speedup 1.0000x reference)
//
#include <hip/hip_runtime.h>
#include <hip/hip_cooperative_groups.h>
#include <hip/hip_fp16.h>
#include <math.h>

namespace cg = cooperative_groups;

#define NMODES 64
#define SDIM   1024
#define BATCH  256
#define PDIM   4096
#define HDIM   128

typedef _Float16 half8  __attribute__((ext_vector_type(8)));
typedef _Float16 half4v __attribute__((ext_vector_type(4)));
typedef float    f32x4  __attribute__((ext_vector_type(4)));

// f16 LDS leading dim: 136 halves = 272 B rows -> 2-way bank alias only (free).
#define LDW 136

// ws: only branch_out f16 [256][128] (64 KB). t3 never leaves LDS now.

// ---------------------------------------------------------------------------
// Single cooperative kernel, 256 blocks x 512 threads (1 block/CU, 8 waves).
// Phase A: fourier + branch MLP for row b -> branch_out (global, 64 KB f16);
//          W2 -> LDS, trunk features -> LDS.
// grid.sync()
// Phase B: trunk MLP for the block's 16-point stripe (t3 tile stays in LDS),
//          then einsum out[0..255][pbase..pbase+15] with A-frags read directly
//          from L2-hot branch_out. No t3 global round-trip, no second launch.
// ---------------------------------------------------------------------------
__global__ __launch_bounds__(512, 1) void k_all(
    const float* __restrict__ u0,
    const float* __restrict__ xv, const float* __restrict__ tv,
    const float* __restrict__ bw1, const float* __restrict__ bb1,
    const float* __restrict__ bw2, const float* __restrict__ bb2,
    const float* __restrict__ bw3, const float* __restrict__ bb3,
    const float* __restrict__ tw1, const float* __restrict__ tb1,
    const float* __restrict__ tw2, const float* __restrict__ tb2,
    const float* __restrict__ tw3, const float* __restrict__ tb3,
    __half* __restrict__ branch_out, float* __restrict__ out) {
    __shared__ _Float16 Ws[128 * LDW];   // 34.8 KB: W2 then W3 (f16)
    __shared__ _Float16 t3L[16 * LDW];   // 4.35 KB: trunk output tile
    __shared__ float    feat[16][4];
    __shared__ union {
        struct {                          // phase A (7.7 KB)
            float u0row[SDIM];
            float part[4][HDIM];
            float fr[HDIM];
            float hh[HDIM];
            float g2[HDIM];
        } fb;
        struct {                          // phase B (8.7 KB)
            _Float16 h1[16 * LDW];
            _Float16 h2[16 * LDW];
        } tr;
    } ax;                                 // total static LDS ~48 KB

    const int t = threadIdx.x;
    const int b = blockIdx.x;
    const int pbase = b * 16;

    // ---------------- phase A ----------------
    // stage u0 row b (coalesced float4)
    if (t < 256)
        ((float4*)ax.fb.u0row)[t] = ((const float4*)(u0 + (size_t)b * SDIM))[t];
    // stage W2 -> LDS f16 (coalesced, 8 float4/thread); needed only after
    // grid.sync but issued here so it drains under phase-A compute.
#pragma unroll
    for (int i = 0; i < 8; ++i) {
        int F = i * 512 + t;                       // float4 index 0..4095
        float4 wv = ((const float4*)tw2)[F];
        half4v h; h.x = (_Float16)wv.x; h.y = (_Float16)wv.y;
        h.z = (_Float16)wv.z; h.w = (_Float16)wv.w;
        *(half4v*)&Ws[(F >> 5) * LDW + (F & 31) * 4] = h;
    }
    if (t < 16) {
        int p = pbase + t;
        float x = xv[p], tt = tv[p];
        float qq = tt * tt - x * x;
        feat[t][0] = x;
        feat[t][1] = tt;
        feat[t][2] = (qq > 0.f) ? sqrtf(qq) : 0.f;
        feat[t][3] = (fabsf(x) <= tt) ? 1.f : 0.f;
    }
    __syncthreads();

    // fourier: rev(s) = k*s/1023 - k/2, fma off a running s (1-op chain),
    // fract, hw v_cos/v_sin (revolutions). S split 4-way -> 256 iters/wave.
    {
        const int j = t & 127, sh = t >> 7;
        const int kmode = (j & 63) + 1;
        const float r  = (float)kmode * (1.0f / 1023.0f);
        const float a0 = -0.5f * (float)kmode;
        float sf = (float)(sh * 256);
        const float* up = ax.fb.u0row + sh * 256;
        float acc = 0.f;
        if ((j & 64) == 0) {                       // wave-uniform branch
#pragma unroll 8
            for (int s = 0; s < 256; ++s) {
                float a = fmaf(sf, r, a0);
                a -= floorf(a);
                acc = fmaf(__builtin_amdgcn_cosf(a), up[s], acc);
                sf += 1.0f;
            }
        } else {
#pragma unroll 8
            for (int s = 0; s < 256; ++s) {
                float a = fmaf(sf, r, a0);
                a -= floorf(a);
                acc = fmaf(__builtin_amdgcn_sinf(a), up[s], acc);
                sf += 1.0f;
            }
        }
        ax.fb.part[sh][j] = acc;
    }
    __syncthreads();
    if (t < 128)
        ax.fb.fr[t] = (ax.fb.part[0][t] + ax.fb.part[1][t] +
                       ax.fb.part[2][t] + ax.fb.part[3][t]) * (1.0f / (float)SDIM);
    __syncthreads();

    // branch MLP (f32), one row; weights L2-hot across 256 blocks
    if (t < 128) {
        const float4* wp = (const float4*)(bw1 + (size_t)t * HDIM);
        float c0 = bb1[t];
        for (int i4 = 0; i4 < 32; ++i4) {
            float4 wv = wp[i4];
            float4 x0 = *(const float4*)&ax.fb.fr[i4 * 4];
            c0 += wv.x * x0.x + wv.y * x0.y + wv.z * x0.z + wv.w * x0.w;
        }
        ax.fb.hh[t] = fmaxf(c0, 0.f);
    }
    __syncthreads();
    if (t < 128) {
        const float4* wp = (const float4*)(bw2 + (size_t)t * HDIM);
        float c0 = bb2[t];
        for (int i4 = 0; i4 < 32; ++i4) {
            float4 wv = wp[i4];
            float4 x0 = *(const float4*)&ax.fb.hh[i4 * 4];
            c0 += wv.x * x0.x + wv.y * x0.y + wv.z * x0.z + wv.w * x0.w;
        }
        ax.fb.g2[t] = fmaxf(c0, 0.f);
    }
    __syncthreads();
    if (t < 128) {
        const float4* wp = (const float4*)(bw3 + (size_t)t * HDIM);
        float c0 = bb3[t];
        for (int i4 = 0; i4 < 32; ++i4) {
            float4 wv = wp[i4];
            float4 x0 = *(const float4*)&ax.fb.g2[i4 * 4];
            c0 += wv.x * x0.x + wv.y * x0.y + wv.z * x0.z + wv.w * x0.w;
        }
        branch_out[(size_t)b * HDIM + t] = __float2half(c0);
    }
    __threadfence();                               // release branch_out (device scope)
    cg::this_grid().sync();                        // device-scope barrier + fences

    // ---------------- phase B ----------------
    // trunk L1: 4 -> 128 (f32 VALU) -> h1 f16
    {
        const int j = t & 127, p0 = t >> 7;        // p0 wave-uniform
        float4 w1 = ((const float4*)tw1)[j];
        float b1 = tb1[j];
#pragma unroll
        for (int i = 0; i < 4; ++i) {
            int p = i * 4 + p0;
            float4 f = *(const float4*)feat[p];    // LDS broadcast
            float v = fmaf(w1.x, f.x, fmaf(w1.y, f.y,
                       fmaf(w1.z, f.z, fmaf(w1.w, f.w, b1))));
            ax.tr.h1[p * LDW + j] = (_Float16)fmaxf(v, 0.f);
        }
    }
    __syncthreads();

    const int lane = t & 63, w = t >> 6;
    const int lm = lane & 15, q = lane >> 4;

    // trunk L2 GEMM: h1(16x128) @ W2^T + tb2, relu -> h2 f16
    {
        f32x4 acc = {0.f, 0.f, 0.f, 0.f};
        const _Float16* aB = &ax.tr.h1[lm * LDW + q * 8];
        const _Float16* bB = &Ws[(w * 16 + lm) * LDW + q * 8];
#pragma unroll
        for (int ks = 0; ks < 4; ++ks) {
            half8 af = *(const half8*)(aB + ks * 32);
            half8 bf = *(const half8*)(bB + ks * 32);
            acc = __builtin_amdgcn_mfma_f32_16x16x32_f16(af, bf, acc, 0, 0, 0);
        }
        // C/D layout: col=lane&15, row=(lane>>4)*4+reg (m89-verified)
        int col = w * 16 + lm;
        float bias = tb2[col];
#pragma unroll
        for (int e = 0; e < 4; ++e)
            ax.tr.h2[(q * 4 + e) * LDW + col] = (_Float16)fmaxf(acc[e] + bias, 0.f);
    }
    __syncthreads();                               // Ws (W2) fully consumed

    // stage W3 -> LDS f16
#pragma unroll
    for (int i = 0; i < 8; ++i) {
        int F = i * 512 + t;
        float4 wv = ((const float4*)tw3)[F];
        half4v h; h.x = (_Float16)wv.x; h.y = (_Float16)wv.y;
        h.z = (_Float16)wv.z; h.w = (_Float16)wv.w;
        *(half4v*)&Ws[(F >> 5) * LDW + (F & 31) * 4] = h;
    }
    __syncthreads();

    // trunk L3 GEMM: h2 @ W3^T + tb3 -> t3L (stays in LDS)
    {
        f32x4 acc = {0.f, 0.f, 0.f, 0.f};
        const _Float16* aB = &ax.tr.h2[lm * LDW + q * 8];
        const _Float16* bB = &Ws[(w * 16 + lm) * LDW + q * 8];
#pragma unroll
        for (int ks = 0; ks < 4; ++ks) {
            half8 af = *(const half8*)(aB + ks * 32);
            half8 bf = *(const half8*)(bB + ks * 32);
            acc = __builtin_amdgcn_mfma_f32_16x16x32_f16(af, bf, acc, 0, 0, 0);
        }
        int col = w * 16 + lm;
        float bias = tb3[col];
#pragma unroll
        for (int e = 0; e < 4; ++e)
            t3L[(q * 4 + e) * LDW + col] = (_Float16)(acc[e] + bias);
    }
    __syncthreads();

    // einsum: out[m=0..255][pbase+lm] ; wave w covers m rows 32w..32w+31.
    // A-frags straight from global branch_out (64 KB, L2-hot everywhere).
    {
        float x = xv[pbase + lm], tt = tv[pbase + lm];
        float cz = (fabsf(x) <= tt) ? 1.f : 0.f;
        const _Float16* brp = (const _Float16*)branch_out;
        f32x4 acc0 = {0.f, 0.f, 0.f, 0.f};
        f32x4 acc1 = {0.f, 0.f, 0.f, 0.f};
#pragma unroll
        for (int ks = 0; ks < 4; ++ks) {
            half8 bf  = *(const half8*)&t3L[lm * LDW + q * 8 + ks * 32];
            half8 af0 = *(const half8*)&brp[(size_t)(w * 32 + lm) * HDIM + q * 8 + ks * 32];
            half8 af1 = *(const half8*)&brp[(size_t)(w * 32 + 16 + lm) * HDIM + q * 8 + ks * 32];
            acc0 = __builtin_amdgcn_mfma_f32_16x16x32_f16(af0, bf, acc0, 0, 0, 0);
            acc1 = __builtin_amdgcn_mfma_f32_16x16x32_f16(af1, bf, acc1, 0, 0, 0);
        }
#pragma unroll
        for (int e = 0; e < 4; ++e) {
            out[(size_t)(w * 32 + q * 4 + e) * PDIM + pbase + lm]      = acc0[e] * cz;
            out[(size_t)(w * 32 + 16 + q * 4 + e) * PDIM + pbase + lm] = acc1[e] * cz;
        }
    }
}

// ---------------------------------------------------------------------------
extern "C" void kernel_launch(void* const* d_in, const int* in_sizes, int n_in,
                              void* d_out, int out_size, void* d_ws, size_t ws_size,
                              hipStream_t stream) {
    const float* u0  = (const float*)d_in[0];
    const float* xv  = (const float*)d_in[1];
    const float* tv  = (const float*)d_in[2];
    const float* bw1 = (const float*)d_in[3];
    const float* bb1 = (const float*)d_in[4];
    const float* bw2 = (const float*)d_in[5];
    const float* bb2 = (const float*)d_in[6];
    const float* bw3 = (const float*)d_in[7];
    const float* bb3 = (const float*)d_in[8];
    const float* tw1 = (const float*)d_in[9];
    const float* tb1 = (const float*)d_in[10];
    const float* tw2 = (const float*)d_in[11];
    const float* tb2 = (const float*)d_in[12];
    const float* tw3 = (const float*)d_in[13];
    const float* tb3 = (const float*)d_in[14];

    __half* branch_out = (__half*)d_ws;
    float* out = (float*)d_out;

    void* args[] = {
        (void*)&u0, (void*)&xv, (void*)&tv,
        (void*)&bw1, (void*)&bb1, (void*)&bw2, (void*)&bb2,
        (void*)&bw3, (void*)&bb3,
        (void*)&tw1, (void*)&tb1, (void*)&tw2, (void*)&tb2,
        (void*)&tw3, (void*)&tb3,
        (void*)&branch_out, (void*)&out,
    };
    hipLaunchCooperativeKernel((const void*)k_all, dim3(256), dim3(512),
                               args, 0, stream);
}

// Round 4
// 103.343 us; speedup vs baseline: 1.7516x; 1.7516x over previous
//
#include <hip/hip_runtime.h>
#include <hip/hip_fp16.h>
#include <math.h>

#define NMODES 64
#define SDIM   1024
#define BATCH  256
#define PDIM   4096
#define HDIM   128

typedef _Float16 half8  __attribute__((ext_vector_type(8)));
typedef _Float16 half4v __attribute__((ext_vector_type(4)));
typedef float    f32x4  __attribute__((ext_vector_type(4)));

// ws layout (bytes):
//   branch @ 0     : f16 [256][128]    (64 KB)
//   t3     @ 65536 : f16 [4096][128]   (1 MB)
#define WSB_BRANCH 0
#define WSB_T3     (BATCH * HDIM * 2)

// f16 LDS leading dim: 136 halves = 272 B rows -> 2-way bank alias only (free).
#define LDW 136

union KMixSmem {
    struct {                       // trunk path (52.7 KB)
        _Float16 Ws[128 * LDW];    // staged weight tile (f16): W2 then W3
        _Float16 h1[32 * LDW];
        _Float16 h2[32 * LDW];
        float    feat[32][4];
    } tr;
    struct {                       // fourier/branch path (~13 KB)
        float u0s[2][SDIM];
        float part[2][2][HDIM];    // [s-half][row][j]
        float fr[2][HDIM];
        float hh[2][HDIM];
        float g2[2][HDIM];
    } fb;
};

// ---------------------------------------------------------------------------
// K1 (256 blocks x 256 thr, exactly 1 block/CU):
//   blocks 0..127   : trunk MLP, 32 points each, L2/L3 via f16 MFMA -> t3 (f16)
//   blocks 128..255 : fourier + branch MLP, 2 rows each (trig amortized 2x,
//                     v_fract instead of floor+sub)
// ---------------------------------------------------------------------------
__global__ __launch_bounds__(256) void k_mix(
    const float* __restrict__ u0,
    const float* __restrict__ xv, const float* __restrict__ tv,
    const float* __restrict__ bw1, const float* __restrict__ bb1,
    const float* __restrict__ bw2, const float* __restrict__ bb2,
    const float* __restrict__ bw3, const float* __restrict__ bb3,
    const float* __restrict__ tw1, const float* __restrict__ tb1,
    const float* __restrict__ tw2, const float* __restrict__ tb2,
    const float* __restrict__ tw3, const float* __restrict__ tb3,
    __half* __restrict__ branch_out, __half* __restrict__ t3g) {
    __shared__ KMixSmem sm;
    const int t = threadIdx.x;

    if (blockIdx.x < 128) {
        // ================= trunk: 32 points, MFMA =================
        const int pbase = blockIdx.x * 32;

        // stage W2 -> LDS f16, fully coalesced (16 float4 / thread)
#pragma unroll
        for (int i = 0; i < 16; ++i) {
            int F = i * 256 + t;                       // float4 index 0..4095
            float4 wv = ((const float4*)tw2)[F];
            half4v h; h.x = (_Float16)wv.x; h.y = (_Float16)wv.y;
            h.z = (_Float16)wv.z; h.w = (_Float16)wv.w;
            *(half4v*)&sm.tr.Ws[(F >> 5) * LDW + (F & 31) * 4] = h;
        }
        if (t < 32) {
            int p = pbase + t;
            float x = xv[p], tt = tv[p];
            float qq = tt * tt - x * x;
            sm.tr.feat[t][0] = x;
            sm.tr.feat[t][1] = tt;
            sm.tr.feat[t][2] = (qq > 0.f) ? sqrtf(qq) : 0.f;
            sm.tr.feat[t][3] = (fabsf(x) <= tt) ? 1.f : 0.f;
        }
        __syncthreads();

        // L1: 4 -> 128 (f32 VALU), write h1 f16
        const int j = t & 127, pg = t >> 7;
        {
            float4 w1 = ((const float4*)tw1)[j];
            float b1 = tb1[j];
#pragma unroll
            for (int i = 0; i < 16; ++i) {
                int p = 2 * i + pg;                    // wave-uniform p -> LDS broadcast
                float4 f = *(const float4*)sm.tr.feat[p];
                float v = fmaf(w1.x, f.x, fmaf(w1.y, f.y,
                           fmaf(w1.z, f.z, fmaf(w1.w, f.w, b1))));
                sm.tr.h1[p * LDW + j] = (_Float16)fmaxf(v, 0.f);
            }
        }
        __syncthreads();

        const int lane = t & 63, w = t >> 6;
        const int lm = lane & 15, q = lane >> 4;
        const int mt = w & 1, nh = w >> 1;             // wave -> (m-tile, n-half)

        // L2 GEMM: h1(32x128) @ W2^T + tb2, relu -> h2 f16
        {
            f32x4 acc[4] = {f32x4{0,0,0,0}, f32x4{0,0,0,0},
                            f32x4{0,0,0,0}, f32x4{0,0,0,0}};
            const _Float16* aB = &sm.tr.h1[(mt * 16 + lm) * LDW + q * 8];
#pragma unroll
            for (int ks = 0; ks < 4; ++ks) {
                half8 af = *(const half8*)(aB + ks * 32);
#pragma unroll
                for (int n = 0; n < 4; ++n) {
                    half8 bf = *(const half8*)
                        &sm.tr.Ws[((nh * 4 + n) * 16 + lm) * LDW + q * 8 + ks * 32];
                    acc[n] = __builtin_amdgcn_mfma_f32_16x16x32_f16(af, bf, acc[n], 0, 0, 0);
                }
            }
            // C/D layout: col=lane&15, row=(lane>>4)*4+reg (m89-verified)
#pragma unroll
            for (int n = 0; n < 4; ++n) {
                int col = (nh * 4 + n) * 16 + lm;
                float b = tb2[col];
#pragma unroll
                for (int e = 0; e < 4; ++e)
                    sm.tr.h2[(mt * 16 + q * 4 + e) * LDW + col] =
                        (_Float16)fmaxf(acc[n][e] + b, 0.f);
            }
        }
        __syncthreads();                               // Ws consumed, h2 ready

        // stage W3 -> LDS f16
#pragma unroll
        for (int i = 0; i < 16; ++i) {
            int F = i * 256 + t;
            float4 wv = ((const float4*)tw3)[F];
            half4v h; h.x = (_Float16)wv.x; h.y = (_Float16)wv.y;
            h.z = (_Float16)wv.z; h.w = (_Float16)wv.w;
            *(half4v*)&sm.tr.Ws[(F >> 5) * LDW + (F & 31) * 4] = h;
        }
        __syncthreads();

        // L3 GEMM: h2 @ W3^T + tb3 -> t3 global f16
        {
            f32x4 acc[4] = {f32x4{0,0,0,0}, f32x4{0,0,0,0},
                            f32x4{0,0,0,0}, f32x4{0,0,0,0}};
            const _Float16* aB = &sm.tr.h2[(mt * 16 + lm) * LDW + q * 8];
#pragma unroll
            for (int ks = 0; ks < 4; ++ks) {
                half8 af = *(const half8*)(aB + ks * 32);
#pragma unroll
                for (int n = 0; n < 4; ++n) {
                    half8 bf = *(const half8*)
                        &sm.tr.Ws[((nh * 4 + n) * 16 + lm) * LDW + q * 8 + ks * 32];
                    acc[n] = __builtin_amdgcn_mfma_f32_16x16x32_f16(af, bf, acc[n], 0, 0, 0);
                }
            }
#pragma unroll
            for (int n = 0; n < 4; ++n) {
                int col = (nh * 4 + n) * 16 + lm;
                float b = tb3[col];
#pragma unroll
                for (int e = 0; e < 4; ++e) {
                    int p = pbase + mt * 16 + q * 4 + e;
                    t3g[(size_t)p * HDIM + col] = __float2half(acc[n][e] + b);
                }
            }
        }
        return;
    }

    // ================= fourier + branch MLP (2 rows) =================
    const int bb = (blockIdx.x - 128) * 2;

    // stage 2 rows of u0 (coalesced float4, 2 per thread)
    {
        int f0 = t;                                    // 0..255 -> row 0
        ((float4*)sm.fb.u0s[0])[f0] = ((const float4*)(u0 + (size_t)bb * SDIM))[f0];
        ((float4*)sm.fb.u0s[1])[f0] = ((const float4*)(u0 + (size_t)(bb + 1) * SDIM))[f0];
    }
    __syncthreads();

    const int j = t & 127, sh = t >> 7;
    {
        // angle in REVOLUTIONS: rev(s) = k*s/1023 - k/2, fma off a running s
        // (carried chain = one v_add), v_fract, hw v_cos/v_sin.
        const int kmode = (j & 63) + 1;
        const float r  = (float)kmode * (1.0f / 1023.0f);
        const float a0 = -0.5f * (float)kmode;
        float sf = (float)(sh * 512);
        const float* u0p = sm.fb.u0s[0] + sh * 512;
        const float* u1p = sm.fb.u0s[1] + sh * 512;
        float acc0 = 0.f, acc1 = 0.f;
        if ((j & 64) == 0) {                           // wave-uniform branch
#pragma unroll 8
            for (int s = 0; s < 512; ++s) {
                float a = __builtin_amdgcn_fractf(fmaf(sf, r, a0));
                float c = __builtin_amdgcn_cosf(a);
                acc0 = fmaf(c, u0p[s], acc0);
                acc1 = fmaf(c, u1p[s], acc1);
                sf += 1.0f;
            }
        } else {
#pragma unroll 8
            for (int s = 0; s < 512; ++s) {
                float a = __builtin_amdgcn_fractf(fmaf(sf, r, a0));
                float c = __builtin_amdgcn_sinf(a);
                acc0 = fmaf(c, u0p[s], acc0);
                acc1 = fmaf(c, u1p[s], acc1);
                sf += 1.0f;
            }
        }
        sm.fb.part[sh][0][j] = acc0;
        sm.fb.part[sh][1][j] = acc1;
    }
    __syncthreads();
    if (t < 128) {
        const float sc = 1.0f / (float)SDIM;
        sm.fb.fr[0][j] = (sm.fb.part[0][0][j] + sm.fb.part[1][0][j]) * sc;
        sm.fb.fr[1][j] = (sm.fb.part[0][1][j] + sm.fb.part[1][1][j]) * sc;
    }
    __syncthreads();

    // branch MLP (f32), two rows; weights L2-hot across 128 blocks
    if (t < 128) {
        const float4* wp = (const float4*)(bw1 + (size_t)j * HDIM);
        float c0 = bb1[j], c1 = c0;
        for (int i4 = 0; i4 < 32; ++i4) {
            float4 wv = wp[i4];
            float4 x0 = *(const float4*)&sm.fb.fr[0][i4 * 4];
            float4 x1 = *(const float4*)&sm.fb.fr[1][i4 * 4];
            c0 += wv.x * x0.x + wv.y * x0.y + wv.z * x0.z + wv.w * x0.w;
            c1 += wv.x * x1.x + wv.y * x1.y + wv.z * x1.z + wv.w * x1.w;
        }
        sm.fb.hh[0][j] = fmaxf(c0, 0.f); sm.fb.hh[1][j] = fmaxf(c1, 0.f);
    }
    __syncthreads();
    if (t < 128) {
        const float4* wp = (const float4*)(bw2 + (size_t)j * HDIM);
        float c0 = bb2[j], c1 = c0;
        for (int i4 = 0; i4 < 32; ++i4) {
            float4 wv = wp[i4];
            float4 x0 = *(const float4*)&sm.fb.hh[0][i4 * 4];
            float4 x1 = *(const float4*)&sm.fb.hh[1][i4 * 4];
            c0 += wv.x * x0.x + wv.y * x0.y + wv.z * x0.z + wv.w * x0.w;
            c1 += wv.x * x1.x + wv.y * x1.y + wv.z * x1.z + wv.w * x1.w;
        }
        sm.fb.g2[0][j] = fmaxf(c0, 0.f); sm.fb.g2[1][j] = fmaxf(c1, 0.f);
    }
    __syncthreads();
    if (t < 128) {
        const float4* wp = (const float4*)(bw3 + (size_t)j * HDIM);
        float c0 = bb3[j], c1 = c0;
        for (int i4 = 0; i4 < 32; ++i4) {
            float4 wv = wp[i4];
            float4 x0 = *(const float4*)&sm.fb.g2[0][i4 * 4];
            float4 x1 = *(const float4*)&sm.fb.g2[1][i4 * 4];
            c0 += wv.x * x0.x + wv.y * x0.y + wv.z * x0.z + wv.w * x0.w;
            c1 += wv.x * x1.x + wv.y * x1.y + wv.z * x1.z + wv.w * x1.w;
        }
        branch_out[(size_t)(bb + 0) * HDIM + j] = __float2half(c0);
        branch_out[(size_t)(bb + 1) * HDIM + j] = __float2half(c1);
    }
}

// ---------------------------------------------------------------------------
// K2: final einsum via fp16 MFMA. out(256x4096) = br(256x128) @ t3^T * causal.
// 256 blocks (4 batch-tiles x 64 point-tiles of 64x64).
// ---------------------------------------------------------------------------
#define LDH 136
__global__ __launch_bounds__(256) void k_final(
    const __half* __restrict__ br_g, const __half* __restrict__ t3g,
    const float* __restrict__ xv, const float* __restrict__ tv,
    float* __restrict__ out) {
    __shared__ _Float16 brL[64 * LDH];
    __shared__ _Float16 ttL[64 * LDH];
    __shared__ float causL[64];

    const int t = threadIdx.x;
    const int rb = blockIdx.x >> 6;   // batch tile 0..3
    const int cb = blockIdx.x & 63;   // point tile 0..63

    if (t < 64) {
        int p = cb * 64 + t;
        float x = xv[p], tt = tv[p];
        causL[t] = (fabsf(x) <= tt) ? 1.f : 0.f;
    }

#pragma unroll
    for (int it = 0; it < 4; ++it) {
        int flat = t + 256 * it;
        int row = flat >> 4, c = flat & 15;
        *(float4*)&brL[row * LDH + c * 8] =
            *(const float4*)&br_g[(size_t)(rb * 64 + row) * HDIM + c * 8];
        *(float4*)&ttL[row * LDH + c * 8] =
            *(const float4*)&t3g[(size_t)(cb * 64 + row) * HDIM + c * 8];
    }
    __syncthreads();

    const int lane = t & 63;
    const int w = t >> 6;
    const int lm = lane & 15;
    const int q = lane >> 4;

    f32x4 acc[4] = {f32x4{0,0,0,0}, f32x4{0,0,0,0}, f32x4{0,0,0,0}, f32x4{0,0,0,0}};

    const _Float16* aBase = &brL[(16 * w + lm) * LDH + q * 8];
#pragma unroll
    for (int ks = 0; ks < 4; ++ks) {
        half8 af = *(const half8*)(aBase + ks * 32);
#pragma unroll
        for (int jt = 0; jt < 4; ++jt) {
            half8 bf = *(const half8*)&ttL[(16 * jt + lm) * LDH + q * 8 + ks * 32];
            acc[jt] = __builtin_amdgcn_mfma_f32_16x16x32_f16(af, bf, acc[jt], 0, 0, 0);
        }
    }

    // C/D layout: col=lane&15, row=(lane>>4)*4+reg (m89-verified)
#pragma unroll
    for (int jt = 0; jt < 4; ++jt) {
        int col = cb * 64 + 16 * jt + lm;
        float cz = causL[16 * jt + lm];
#pragma unroll
        for (int e = 0; e < 4; ++e) {
            int row = rb * 64 + 16 * w + q * 4 + e;
            out[(size_t)row * PDIM + col] = acc[jt][e] * cz;
        }
    }
}

// ---------------------------------------------------------------------------
extern "C" void kernel_launch(void* const* d_in, const int* in_sizes, int n_in,
                              void* d_out, int out_size, void* d_ws, size_t ws_size,
                              hipStream_t stream) {
    const float* u0  = (const float*)d_in[0];
    const float* xv  = (const float*)d_in[1];
    const float* tv  = (const float*)d_in[2];
    const float* bw1 = (const float*)d_in[3];
    const float* bb1 = (const float*)d_in[4];
    const float* bw2 = (const float*)d_in[5];
    const float* bb2 = (const float*)d_in[6];
    const float* bw3 = (const float*)d_in[7];
    const float* bb3 = (const float*)d_in[8];
    const float* tw1 = (const float*)d_in[9];
    const float* tb1 = (const float*)d_in[10];
    const float* tw2 = (const float*)d_in[11];
    const float* tb2 = (const float*)d_in[12];
    const float* tw3 = (const float*)d_in[13];
    const float* tb3 = (const float*)d_in[14];

    char* wsb = (char*)d_ws;
    __half* branch_out = (__half*)(wsb + WSB_BRANCH);
    __half* t3g        = (__half*)(wsb + WSB_T3);
    float* out = (float*)d_out;

    hipLaunchKernelGGL(k_mix, dim3(256), dim3(256), 0, stream,
                       u0, xv, tv, bw1, bb1, bw2, bb2, bw3, bb3,
                       tw1, tb1, tw2, tb2, tw3, tb3, branch_out, t3g);
    hipLaunchKernelGGL(k_final, dim3(256), dim3(256), 0, stream,
                       branch_out, t3g, xv, tv, out);
}